// Round 7
// baseline (428.555 us; speedup 1.0000x reference)
//
#include <hip/hip_runtime.h>
#include <hip/hip_bf16.h>
#include <math.h>

typedef unsigned int u32;
typedef unsigned long long u64;

#define NCLS 80
#define KLVL 1000
#define CAP  8192
#define TARGET_S 160u   // sampled (1/16) cum target -> true count ~2600 +- 210

// workspace byte offsets (all 16B aligned)
#define OFF_CAND   0u        // u64 [3][8192]
#define OFF_HIST   196608u   // u32 [3][2048]
#define OFF_CNT    221184u   // u32 [8]: [0..2]=cand counts, [4..6]=threshold bits
#define OFF_GFLAT  221216u   // u32 [3000]
#define OFF_GSB    233216u   // u32 [3000]
#define OFF_QX1    245216u   // f32 [3000] (rank-indexed NMS coords)
#define OFF_QY1    257216u
#define OFF_QX2    269216u
#define OFF_QY2    281216u
#define OFF_AREA   293216u
#define OFF_SCORE  305216u
#define OFF_LABEL  317216u   // u32
#define OFF_VALID  329216u   // u32
#define OFF_OBOX   341216u   // f32 [3000][4]

__constant__ float cANCH[3][3][2] = {
  {{10.f,13.f},{16.f,30.f},{33.f,23.f}},
  {{30.f,61.f},{62.f,45.f},{59.f,119.f}},
  {{116.f,90.f},{156.f,198.f},{373.f,326.f}}
};

// cheap sigmoid: histogram binning / prefilter only (64-ulp slack covers error)
__device__ __forceinline__ float sig_fast(float x) {
  return 1.0f / (1.0f + __expf(-x));
}
// critical sigmoid: f32 steps, near-correctly-rounded exp via f64
__device__ __forceinline__ float sig_crit(float x) {
#pragma clang fp contract(off)
  double e = exp(-(double)x);
  float ef = (float)e;
  return 1.0f / (1.0f + ef);
}

// ---- kA: zero hist / counters / per-level topk buffers ----
__global__ __launch_bounds__(256) void kA(u32* __restrict__ hist,
                                          u32* __restrict__ cnt,
                                          u32* __restrict__ gsbits,
                                          u32* __restrict__ gflat) {
  int t = blockIdx.x * 256 + threadIdx.x;
  if (t < 6144) hist[t] = 0u;
  else if (t < 6152) cnt[t - 6144] = 0u;
  else if (t < 9152) gsbits[t - 6152] = 0u;
  else if (t < 12152) gflat[t - 9152] = 0u;
}

// ---- kB_s: SAMPLED (1/16 chunks) histogram of cheap product bits ----
__global__ __launch_bounds__(256) void kB_s(const float* __restrict__ c0,
                                            const float* __restrict__ c1,
                                            const float* __restrict__ c2,
                                            const float* __restrict__ o0,
                                            const float* __restrict__ o1,
                                            const float* __restrict__ o2,
                                            u32* __restrict__ ghist) {
  __shared__ u32 lh[2048];
  for (int i = threadIdx.x; i < 2048; i += 256) lh[i] = 0u;
  __syncthreads();
  int bid = blockIdx.x;
  int l, e0; const float* cls; const float* obj;
  if (bid < 375)      { l = 0; e0 = (bid * 16 + 8) * 1024;         cls = c0; obj = o0; }
  else if (bid < 469) { l = 1; e0 = ((bid - 375) * 16 + 8) * 1024; cls = c1; obj = o1; }
  else                { l = 2; e0 = ((bid - 469) * 16 + 8) * 1024; cls = c2; obj = o2; }
  int e = e0 + threadIdx.x * 4;
  float4 cv = *(const float4*)(cls + e);
  float so = sig_fast(obj[e / 80]);
  float cc[4] = {cv.x, cv.y, cv.z, cv.w};
#pragma unroll
  for (int k = 0; k < 4; k++) {
    float p = so * sig_fast(cc[k]);
    atomicAdd(&lh[__float_as_uint(p) >> 19], 1u);
  }
  __syncthreads();
  for (int i = threadIdx.x; i < 2048; i += 256) {
    u32 v = lh[i];
    if (v) atomicAdd(&ghist[l * 2048 + i], v);
  }
}

// ---- k2: wave-parallel threshold pick (suffix cum from top >= TARGET_S) ----
__global__ __launch_bounds__(64) void k2(const u32* __restrict__ ghist,
                                         u32* __restrict__ cnt) {
  int l = blockIdx.x;
  int lane = threadIdx.x;
  const u32* h = ghist + l * 2048;
  int top = 2047 - lane * 32;          // lane's window: bins [top-31 .. top]
  u32 s = 0;
#pragma unroll
  for (int i = 0; i < 32; i++) s += h[top - i];
  u32 pre = s;                          // inclusive scan over lanes (from top)
#pragma unroll
  for (int off = 1; off < 64; off <<= 1) {
    u32 o = __shfl_up(pre, off);
    if (lane >= off) pre += o;
  }
  u64 m = __ballot(pre >= TARGET_S);
  if (m == 0ull) { if (lane == 0) cnt[4 + l] = 0u; return; }
  int sel = __ffsll((long long)m) - 1;
  if (lane == sel) {
    u32 c = pre - s;
    u32 bb = 0u;
    for (int i = 0; i < 32; i++) {
      c += h[top - i];
      if (c >= TARGET_S) { bb = (u32)(top - i); break; }
    }
    cnt[4 + l] = bb << 19;
  }
}

// block -> (level, elem base) for full passes
__device__ __forceinline__ void block_map(int bid, int& l, int& e0) {
  if (bid < 6000)      { l = 0; e0 = bid * 1024; }
  else if (bid < 7500) { l = 1; e0 = (bid - 6000) * 1024; }
  else                 { l = 2; e0 = (bid - 7500) * 1024; }
}

// ---- k3: compact candidates with exact score bits >= T ----
__global__ __launch_bounds__(256) void k3(const float* __restrict__ c0,
                                          const float* __restrict__ c1,
                                          const float* __restrict__ c2,
                                          const float* __restrict__ o0,
                                          const float* __restrict__ o1,
                                          const float* __restrict__ o2,
                                          u32* __restrict__ cnt,
                                          u64* __restrict__ cand) {
  int l, e0; block_map(blockIdx.x, l, e0);
  const float* cls = (l == 0) ? c0 : (l == 1) ? c1 : c2;
  const float* obj = (l == 0) ? o0 : (l == 1) ? o1 : o2;
  u32 T = cnt[4 + l];
  u32 Tm = (T > 64u) ? (T - 64u) : 0u;
  int e = e0 + threadIdx.x * 4;
  float4 cv = *(const float4*)(cls + e);
  int a = e / 80;
  float so = sig_fast(obj[a]);
  float cc[4] = {cv.x, cv.y, cv.z, cv.w};
#pragma unroll
  for (int k = 0; k < 4; k++) {
    float pch = so * sig_fast(cc[k]);
    if (__float_as_uint(pch) >= Tm) {
      float soe = sig_crit(obj[a]);
      float sce = sig_crit(cc[k]);
      float p = soe * sce;
      u32 bits = __float_as_uint(p);
      if (bits >= T) {
        u32 slot = atomicAdd(&cnt[l], 1u);
        if (slot < CAP) {
          float s = __fsqrt_rn(p);
          u64 key = ((u64)__float_as_uint(s) << 32) | (u32)(~((u32)(e + k)));
          cand[(size_t)l * CAP + slot] = key;
        }
      }
    }
  }
}

// ---- r1: per-level rank-by-counting via UNIFORM global scan (s_load path) ----
__global__ __launch_bounds__(256) void r1(const u64* __restrict__ cand,
                                          const u32* __restrict__ cnt,
                                          u32* __restrict__ gsbits,
                                          u32* __restrict__ gflat) {
  int l = blockIdx.x >> 5;        // 32 blocks per level
  int b = blockIdx.x & 31;
  u32 n = cnt[l]; if (n > CAP) n = CAP;
  u32 idx = (u32)(b * 256 + threadIdx.x);
  if (idx >= n) return;
  const u64* base = cand + (size_t)l * CAP;
  u64 my = base[idx];
  u32 rank = 0;
#pragma unroll 8
  for (u32 i = 0; i < n; ++i) rank += (base[i] > my) ? 1u : 0u;
  if (rank < KLVL) {
    gsbits[l * KLVL + rank] = (u32)(my >> 32);
    gflat [l * KLVL + rank] = ~((u32)my);
  }
}

// ---- rk6: global rank (uniform scan) + decode + default outputs ----
__global__ __launch_bounds__(256) void rk6(const float* __restrict__ r0,
                                           const float* __restrict__ r1_,
                                           const float* __restrict__ r2_,
                                           const u32* __restrict__ gsbits,
                                           const u32* __restrict__ gflat,
                                           float* __restrict__ qx1, float* __restrict__ qy1,
                                           float* __restrict__ qx2, float* __restrict__ qy2,
                                           float* __restrict__ area,
                                           float* __restrict__ score,
                                           u32* __restrict__ label,
                                           u32* __restrict__ valid,
                                           float* __restrict__ obox,
                                           float* __restrict__ out) {
#pragma clang fp contract(off)
  int t = blockIdx.x * 256 + threadIdx.x;
  if (t >= 3000) return;
  // defaults for slot t (k7 overwrites kept boxes only)
  ((float4*)out)[t] = make_float4(0.f, 0.f, 0.f, 0.f);
  out[12000 + t] = 0.0f;
  out[15000 + t] = -1.0f;
  out[18000 + t] = 0.0f;
  u32 myb = gsbits[t];
  u64 my = (((u64)myb) << 32) | (u32)(~t);
  u32 rank = 0;
#pragma unroll 8
  for (int i = 0; i < 3000; ++i) {
    u64 k = (((u64)gsbits[i]) << 32) | (u32)(~i);
    rank += (k > my) ? 1u : 0u;
  }
  // decode own entry, scatter to slot = rank
  int l = t / 1000;
  u32 flat = gflat[t];
  float sc = __uint_as_float(myb);
  int a = (int)(flat / NCLS), c = (int)(flat % NCLS);
  int cell = a / 3, bi = a % 3;
  int f = (l == 0) ? 160 : (l == 1) ? 80 : 40;
  float stride = (float)(8 << l);
  float gx = (float)(cell % f), gy = (float)(cell / f);
  const float* rp = ((l == 0) ? r0 : (l == 1) ? r1_ : r2_) + (size_t)a * 4;
  float t0 = rp[0], t1 = rp[1], t2 = rp[2], t3 = rp[3];
  float sx = 1.0f / (1.0f + expf(-t0));
  float sy = 1.0f / (1.0f + expf(-t1));
  float w = expf(t2) * cANCH[l][bi][0];
  float h = expf(t3) * cANCH[l][bi][1];
  float cx = (sx + gx) * stride;
  float cy = (sy + gy) * stride;
  float hw = w * 0.5f, hh = h * 0.5f;
  float x1 = cx - hw, y1 = cy - hh, x2 = cx + hw, y2 = cy + hh;
  ((float4*)obox)[rank] = make_float4(x1, y1, x2, y2);
  // reference NMS treats [x1,y1,x2,y2] as [cx,cy,w,h]
  float hx2 = x2 * 0.5f, hy2 = y2 * 0.5f;
  float bx1 = x1 - hx2, by1 = y1 - hy2, bx2 = x1 + hx2, by2 = y1 + hy2;
  float off = (float)c * 1e7f;              // f32 quantization is load-bearing
  float a1 = bx1 + off, a2 = bx2 + off;
  qx1[rank] = a1; qy1[rank] = by1; qx2[rank] = a2; qy2[rank] = by2;
  area[rank] = (a2 - a1) * (by2 - by1);
  score[rank] = sc; label[rank] = (u32)c;
  valid[rank] = (sc > 0.3f) ? 1u : 0u;
}

// ---- k7: per-class greedy NMS + final output writes for kept boxes ----
#define CAPC 1024
__global__ __launch_bounds__(64) void k7(const float* __restrict__ qx1,
                                         const float* __restrict__ qy1,
                                         const float* __restrict__ qx2,
                                         const float* __restrict__ qy2,
                                         const float* __restrict__ area,
                                         const float* __restrict__ score,
                                         const u32* __restrict__ label,
                                         const u32* __restrict__ valid,
                                         const float* __restrict__ obox,
                                         float* __restrict__ out) {
#pragma clang fp contract(off)
  __shared__ u32 LIST[CAPC];
  __shared__ float X1[CAPC], Y1[CAPC], X2[CAPC], Y2[CAPC], AR[CAPC];
  __shared__ u32 KP[CAPC];
  u32 c = blockIdx.x;
  int lane = threadIdx.x;
  u32 n = 0;
  for (int base = 0; base < 3000; base += 64) {
    int j = base + lane;
    bool m = false;
    if (j < 3000) m = (label[j] == c) && (valid[j] != 0u);
    u64 mask = __ballot(m ? 1 : 0);
    u32 pos = n + (u32)__popcll(mask & ((1ull << lane) - 1ull));
    if (m && pos < CAPC) {
      LIST[pos] = (u32)j;
      X1[pos] = qx1[j]; Y1[pos] = qy1[j];
      X2[pos] = qx2[j]; Y2[pos] = qy2[j];
      AR[pos] = area[j]; KP[pos] = 1u;
    }
    n += (u32)__popcll(mask);
  }
  if (n > CAPC) n = CAPC;
  __syncthreads();
  for (u32 i = 0; i < n; ++i) {
    if (KP[i]) {
      float xi1 = X1[i], yi1 = Y1[i], xi2 = X2[i], yi2 = Y2[i], ai = AR[i];
      for (u32 j = i + 1 + (u32)lane; j < n; j += 64) {
        if (KP[j]) {
          float xx1 = fmaxf(xi1, X1[j]);
          float yy1 = fmaxf(yi1, Y1[j]);
          float xx2 = fminf(xi2, X2[j]);
          float yy2 = fminf(yi2, Y2[j]);
          float iw = xx2 - xx1, ih = yy2 - yy1;
          float inter = fmaxf(1e-10f, iw) * fmaxf(1e-10f, ih);
          float den = ai + AR[j] - inter + 1e-14f;
          if (inter / den > 0.5f) KP[j] = 0u;
        }
      }
    }
    __syncthreads();
  }
  for (u32 j = (u32)lane; j < n; j += 64) {
    if (KP[j]) {
      u32 r = LIST[j];
      float4 bx = ((const float4*)obox)[r];
      ((float4*)out)[r] = bx;
      out[12000 + r] = score[r];
      out[15000 + r] = (float)(int)c;
      out[18000 + r] = 1.0f;
    }
  }
}

extern "C" void kernel_launch(void* const* d_in, const int* in_sizes, int n_in,
                              void* d_out, int out_size, void* d_ws, size_t ws_size,
                              hipStream_t stream) {
  const float* obj0 = (const float*)d_in[0];
  const float* cls0 = (const float*)d_in[1];
  const float* reg0 = (const float*)d_in[2];
  const float* obj1 = (const float*)d_in[3];
  const float* cls1 = (const float*)d_in[4];
  const float* reg1 = (const float*)d_in[5];
  const float* obj2 = (const float*)d_in[6];
  const float* cls2 = (const float*)d_in[7];
  const float* reg2 = (const float*)d_in[8];
  char* ws = (char*)d_ws;
  u64* cand   = (u64*)(ws + OFF_CAND);
  u32* hist   = (u32*)(ws + OFF_HIST);
  u32* cnt    = (u32*)(ws + OFF_CNT);
  u32* gflat  = (u32*)(ws + OFF_GFLAT);
  u32* gsbits = (u32*)(ws + OFF_GSB);
  float* qx1  = (float*)(ws + OFF_QX1);
  float* qy1  = (float*)(ws + OFF_QY1);
  float* qx2  = (float*)(ws + OFF_QX2);
  float* qy2  = (float*)(ws + OFF_QY2);
  float* area = (float*)(ws + OFF_AREA);
  float* score= (float*)(ws + OFF_SCORE);
  u32* label  = (u32*)(ws + OFF_LABEL);
  u32* valid  = (u32*)(ws + OFF_VALID);
  float* obox = (float*)(ws + OFF_OBOX);
  float* out  = (float*)d_out;

  kA<<<48, 256, 0, stream>>>(hist, cnt, gsbits, gflat);
  kB_s<<<492, 256, 0, stream>>>(cls0, cls1, cls2, obj0, obj1, obj2, hist);
  k2<<<3, 64, 0, stream>>>(hist, cnt);
  k3<<<7875, 256, 0, stream>>>(cls0, cls1, cls2, obj0, obj1, obj2, cnt, cand);
  r1<<<96, 256, 0, stream>>>(cand, cnt, gsbits, gflat);
  rk6<<<12, 256, 0, stream>>>(reg0, reg1, reg2, gsbits, gflat,
                              qx1, qy1, qx2, qy2, area, score, label, valid, obox, out);
  k7<<<80, 64, 0, stream>>>(qx1, qy1, qx2, qy2, area, score, label, valid, obox, out);
}

// Round 9
// 332.067 us; speedup vs baseline: 1.2906x; 1.2906x over previous
//
#include <hip/hip_runtime.h>
#include <hip/hip_bf16.h>
#include <math.h>

typedef unsigned int u32;
typedef unsigned long long u64;

#define NCLS 80
#define KLVL 1000
#define CAP  8192
#define TARGET_S 160u   // sampled (1/16) cum target -> true count ~2600 +- 210

// workspace byte offsets (all 16B aligned)
#define OFF_CAND   0u        // u64 [3][8192]
#define OFF_HIST   196608u   // u32 [3][2048]
#define OFF_CNT    221184u   // u32 [8]: [0..2]=cand counts, [4..6]=threshold bits
#define OFF_GFLAT  221216u   // u32 [3000]
#define OFF_GSB    233216u   // u32 [3000]
#define OFF_QX1    245216u   // f32 [3000] (rank-indexed NMS coords)
#define OFF_QY1    257216u
#define OFF_QX2    269216u
#define OFF_QY2    281216u
#define OFF_AREA   293216u
#define OFF_SCORE  305216u
#define OFF_LABEL  317216u   // u32
#define OFF_VALID  329216u   // u32
#define OFF_OBOX   341216u   // f32 [3000][4]

__constant__ float cANCH[3][3][2] = {
  {{10.f,13.f},{16.f,30.f},{33.f,23.f}},
  {{30.f,61.f},{62.f,45.f},{59.f,119.f}},
  {{116.f,90.f},{156.f,198.f},{373.f,326.f}}
};

// cheap sigmoid: histogram binning / prefilter only (64-ulp slack covers error)
__device__ __forceinline__ float sig_fast(float x) {
  return 1.0f / (1.0f + __expf(-x));
}
// critical sigmoid: f32 steps, near-correctly-rounded exp via f64
__device__ __forceinline__ float sig_crit(float x) {
#pragma clang fp contract(off)
  double e = exp(-(double)x);
  float ef = (float)e;
  return 1.0f / (1.0f + ef);
}

// ---- kA: zero hist / counters / per-level topk buffers ----
__global__ __launch_bounds__(256) void kA(u32* __restrict__ hist,
                                          u32* __restrict__ cnt,
                                          u32* __restrict__ gsbits,
                                          u32* __restrict__ gflat) {
  int t = blockIdx.x * 256 + threadIdx.x;
  if (t < 6144) hist[t] = 0u;
  else if (t < 6152) cnt[t - 6144] = 0u;
  else if (t < 9152) gsbits[t - 6152] = 0u;
  else if (t < 12152) gflat[t - 9152] = 0u;
}

// ---- kB_s: SAMPLED (1/16 chunks) histogram of cheap product bits ----
__global__ __launch_bounds__(256) void kB_s(const float* __restrict__ c0,
                                            const float* __restrict__ c1,
                                            const float* __restrict__ c2,
                                            const float* __restrict__ o0,
                                            const float* __restrict__ o1,
                                            const float* __restrict__ o2,
                                            u32* __restrict__ ghist) {
  __shared__ u32 lh[2048];
  for (int i = threadIdx.x; i < 2048; i += 256) lh[i] = 0u;
  __syncthreads();
  int bid = blockIdx.x;
  int l, e0; const float* cls; const float* obj;
  if (bid < 375)      { l = 0; e0 = (bid * 16 + 8) * 1024;         cls = c0; obj = o0; }
  else if (bid < 469) { l = 1; e0 = ((bid - 375) * 16 + 8) * 1024; cls = c1; obj = o1; }
  else                { l = 2; e0 = ((bid - 469) * 16 + 8) * 1024; cls = c2; obj = o2; }
  int e = e0 + threadIdx.x * 4;
  float4 cv = *(const float4*)(cls + e);
  float so = sig_fast(obj[e / 80]);
  float cc[4] = {cv.x, cv.y, cv.z, cv.w};
#pragma unroll
  for (int k = 0; k < 4; k++) {
    float p = so * sig_fast(cc[k]);
    atomicAdd(&lh[__float_as_uint(p) >> 19], 1u);
  }
  __syncthreads();
  for (int i = threadIdx.x; i < 2048; i += 256) {
    u32 v = lh[i];
    if (v) atomicAdd(&ghist[l * 2048 + i], v);
  }
}

// ---- k2: wave-parallel threshold pick (suffix cum from top >= TARGET_S) ----
__global__ __launch_bounds__(64) void k2(const u32* __restrict__ ghist,
                                         u32* __restrict__ cnt) {
  int l = blockIdx.x;
  int lane = threadIdx.x;
  const u32* h = ghist + l * 2048;
  int top = 2047 - lane * 32;          // lane's window: bins [top-31 .. top]
  u32 s = 0;
#pragma unroll
  for (int i = 0; i < 32; i++) s += h[top - i];
  u32 pre = s;                          // inclusive scan over lanes (from top)
#pragma unroll
  for (int off = 1; off < 64; off <<= 1) {
    u32 o = __shfl_up(pre, off);
    if (lane >= off) pre += o;
  }
  u64 m = __ballot(pre >= TARGET_S);
  if (m == 0ull) { if (lane == 0) cnt[4 + l] = 0u; return; }
  int sel = __ffsll((long long)m) - 1;
  if (lane == sel) {
    u32 c = pre - s;
    u32 bb = 0u;
    for (int i = 0; i < 32; i++) {
      c += h[top - i];
      if (c >= TARGET_S) { bb = (u32)(top - i); break; }
    }
    cnt[4 + l] = bb << 19;
  }
}

// block -> (level, elem base) for full passes
__device__ __forceinline__ void block_map(int bid, int& l, int& e0) {
  if (bid < 6000)      { l = 0; e0 = bid * 1024; }
  else if (bid < 7500) { l = 1; e0 = (bid - 6000) * 1024; }
  else                 { l = 2; e0 = (bid - 7500) * 1024; }
}

// ---- k3: compact candidates with exact score bits >= T ----
__global__ __launch_bounds__(256) void k3(const float* __restrict__ c0,
                                          const float* __restrict__ c1,
                                          const float* __restrict__ c2,
                                          const float* __restrict__ o0,
                                          const float* __restrict__ o1,
                                          const float* __restrict__ o2,
                                          u32* __restrict__ cnt,
                                          u64* __restrict__ cand) {
  int l, e0; block_map(blockIdx.x, l, e0);
  const float* cls = (l == 0) ? c0 : (l == 1) ? c1 : c2;
  const float* obj = (l == 0) ? o0 : (l == 1) ? o1 : o2;
  u32 T = cnt[4 + l];
  u32 Tm = (T > 64u) ? (T - 64u) : 0u;
  int e = e0 + threadIdx.x * 4;
  float4 cv = *(const float4*)(cls + e);
  int a = e / 80;
  float so = sig_fast(obj[a]);
  float cc[4] = {cv.x, cv.y, cv.z, cv.w};
#pragma unroll
  for (int k = 0; k < 4; k++) {
    float pch = so * sig_fast(cc[k]);
    if (__float_as_uint(pch) >= Tm) {
      float soe = sig_crit(obj[a]);
      float sce = sig_crit(cc[k]);
      float p = soe * sce;
      u32 bits = __float_as_uint(p);
      if (bits >= T) {
        u32 slot = atomicAdd(&cnt[l], 1u);
        if (slot < CAP) {
          float s = __fsqrt_rn(p);
          u64 key = ((u64)__float_as_uint(s) << 32) | (u32)(~((u32)(e + k)));
          cand[(size_t)l * CAP + slot] = key;
        }
      }
    }
  }
}

// ---- r1: per-level rank-by-counting. One wave per block, one candidate per
// lane; scan runs over an LDS-staged copy with wave-uniform BROADCAST reads
// (1 ds_read_b64/wave/elem, conflict-free) — NOT latency-exposed global loads.
__global__ __launch_bounds__(64) void r1(const u64* __restrict__ cand,
                                         const u32* __restrict__ cnt,
                                         u32* __restrict__ gsbits,
                                         u32* __restrict__ gflat) {
  __shared__ u64 S[CAP];
  int l = blockIdx.x >> 7;        // 128 blocks per level
  int b = blockIdx.x & 127;
  u32 n = cnt[l]; if (n > CAP) n = CAP;
  if ((u32)(b * 64) >= n) return;        // wave-uniform early exit
  const u64* base = cand + (size_t)l * CAP;
  for (u32 i = threadIdx.x; i < n; i += 64) S[i] = base[i];   // coalesced stage
  __syncthreads();
  u32 idx = (u32)(b * 64 + threadIdx.x);
  u64 my = (idx < n) ? S[idx] : 0ull;
  u32 rank = 0;
#pragma unroll 8
  for (u32 i = 0; i < n; ++i) rank += (S[i] > my) ? 1u : 0u;  // broadcast reads
  if (idx < n && rank < KLVL) {
    gsbits[l * KLVL + rank] = (u32)(my >> 32);
    gflat [l * KLVL + rank] = ~((u32)my);
  }
}

// ---- rk6: global rank (LDS broadcast scan) + decode + default outputs ----
__global__ __launch_bounds__(64) void rk6(const float* __restrict__ r0,
                                          const float* __restrict__ r1_,
                                          const float* __restrict__ r2_,
                                          const u32* __restrict__ gsbits,
                                          const u32* __restrict__ gflat,
                                          float* __restrict__ qx1, float* __restrict__ qy1,
                                          float* __restrict__ qx2, float* __restrict__ qy2,
                                          float* __restrict__ area,
                                          float* __restrict__ score,
                                          u32* __restrict__ label,
                                          u32* __restrict__ valid,
                                          float* __restrict__ obox,
                                          float* __restrict__ out) {
#pragma clang fp contract(off)
  __shared__ u32 SB[3000];
  int t = blockIdx.x * 64 + threadIdx.x;   // 47 blocks x 64
  for (u32 i = threadIdx.x; i < 3000; i += 64) SB[i] = gsbits[i];
  __syncthreads();
  if (t >= 3000) return;
  // defaults for slot t (k7 overwrites kept boxes only)
  ((float4*)out)[t] = make_float4(0.f, 0.f, 0.f, 0.f);
  out[12000 + t] = 0.0f;
  out[15000 + t] = -1.0f;
  out[18000 + t] = 0.0f;
  u32 myb = SB[t];
  u64 my = (((u64)myb) << 32) | (u32)(~t);
  u32 rank = 0;
#pragma unroll 8
  for (int i = 0; i < 3000; ++i) {         // broadcast reads, uniform i
    u64 k = (((u64)SB[i]) << 32) | (u32)(~i);
    rank += (k > my) ? 1u : 0u;
  }
  // decode own entry, scatter to slot = rank
  int l = t / 1000;
  u32 flat = gflat[t];
  float sc = __uint_as_float(myb);
  int a = (int)(flat / NCLS), c = (int)(flat % NCLS);
  int cell = a / 3, bi = a % 3;
  int f = (l == 0) ? 160 : (l == 1) ? 80 : 40;
  float stride = (float)(8 << l);
  float gx = (float)(cell % f), gy = (float)(cell / f);
  const float* rp = ((l == 0) ? r0 : (l == 1) ? r1_ : r2_) + (size_t)a * 4;
  float t0 = rp[0], t1 = rp[1], t2 = rp[2], t3 = rp[3];
  float sx = 1.0f / (1.0f + expf(-t0));
  float sy = 1.0f / (1.0f + expf(-t1));
  float w = expf(t2) * cANCH[l][bi][0];
  float h = expf(t3) * cANCH[l][bi][1];
  float cx = (sx + gx) * stride;
  float cy = (sy + gy) * stride;
  float hw = w * 0.5f, hh = h * 0.5f;
  float x1 = cx - hw, y1 = cy - hh, x2 = cx + hw, y2 = cy + hh;
  ((float4*)obox)[rank] = make_float4(x1, y1, x2, y2);
  // reference NMS treats [x1,y1,x2,y2] as [cx,cy,w,h]
  float hx2 = x2 * 0.5f, hy2 = y2 * 0.5f;
  float bx1 = x1 - hx2, by1 = y1 - hy2, bx2 = x1 + hx2, by2 = y1 + hy2;
  float off = (float)c * 1e7f;              // f32 quantization is load-bearing
  float a1 = bx1 + off, a2 = bx2 + off;
  qx1[rank] = a1; qy1[rank] = by1; qx2[rank] = a2; qy2[rank] = by2;
  area[rank] = (a2 - a1) * (by2 - by1);
  score[rank] = sc; label[rank] = (u32)c;
  valid[rank] = (sc > 0.3f) ? 1u : 0u;
}

// ---- k7: per-class greedy NMS + final output writes for kept boxes ----
#define CAPC 1024
__global__ __launch_bounds__(64) void k7(const float* __restrict__ qx1,
                                         const float* __restrict__ qy1,
                                         const float* __restrict__ qx2,
                                         const float* __restrict__ qy2,
                                         const float* __restrict__ area,
                                         const float* __restrict__ score,
                                         const u32* __restrict__ label,
                                         const u32* __restrict__ valid,
                                         const float* __restrict__ obox,
                                         float* __restrict__ out) {
#pragma clang fp contract(off)
  __shared__ u32 LIST[CAPC];
  __shared__ float X1[CAPC], Y1[CAPC], X2[CAPC], Y2[CAPC], AR[CAPC];
  __shared__ u32 KP[CAPC];
  u32 c = blockIdx.x;
  int lane = threadIdx.x;
  u32 n = 0;
  for (int base = 0; base < 3000; base += 64) {
    int j = base + lane;
    bool m = false;
    if (j < 3000) m = (label[j] == c) && (valid[j] != 0u);
    u64 mask = __ballot(m ? 1 : 0);
    u32 pos = n + (u32)__popcll(mask & ((1ull << lane) - 1ull));
    if (m && pos < CAPC) {
      LIST[pos] = (u32)j;
      X1[pos] = qx1[j]; Y1[pos] = qy1[j];
      X2[pos] = qx2[j]; Y2[pos] = qy2[j];
      AR[pos] = area[j]; KP[pos] = 1u;
    }
    n += (u32)__popcll(mask);
  }
  if (n > CAPC) n = CAPC;
  __syncthreads();
  for (u32 i = 0; i < n; ++i) {
    if (KP[i]) {
      float xi1 = X1[i], yi1 = Y1[i], xi2 = X2[i], yi2 = Y2[i], ai = AR[i];
      for (u32 j = i + 1 + (u32)lane; j < n; j += 64) {
        if (KP[j]) {
          float xx1 = fmaxf(xi1, X1[j]);
          float yy1 = fmaxf(yi1, Y1[j]);
          float xx2 = fminf(xi2, X2[j]);
          float yy2 = fminf(yi2, Y2[j]);
          float iw = xx2 - xx1, ih = yy2 - yy1;
          float inter = fmaxf(1e-10f, iw) * fmaxf(1e-10f, ih);
          float den = ai + AR[j] - inter + 1e-14f;
          if (inter / den > 0.5f) KP[j] = 0u;
        }
      }
    }
    __syncthreads();
  }
  for (u32 j = (u32)lane; j < n; j += 64) {
    if (KP[j]) {
      u32 r = LIST[j];
      float4 bx = ((const float4*)obox)[r];
      ((float4*)out)[r] = bx;
      out[12000 + r] = score[r];
      out[15000 + r] = (float)(int)c;
      out[18000 + r] = 1.0f;
    }
  }
}

extern "C" void kernel_launch(void* const* d_in, const int* in_sizes, int n_in,
                              void* d_out, int out_size, void* d_ws, size_t ws_size,
                              hipStream_t stream) {
  const float* obj0 = (const float*)d_in[0];
  const float* cls0 = (const float*)d_in[1];
  const float* reg0 = (const float*)d_in[2];
  const float* obj1 = (const float*)d_in[3];
  const float* cls1 = (const float*)d_in[4];
  const float* reg1 = (const float*)d_in[5];
  const float* obj2 = (const float*)d_in[6];
  const float* cls2 = (const float*)d_in[7];
  const float* reg2 = (const float*)d_in[8];
  char* ws = (char*)d_ws;
  u64* cand   = (u64*)(ws + OFF_CAND);
  u32* hist   = (u32*)(ws + OFF_HIST);
  u32* cnt    = (u32*)(ws + OFF_CNT);
  u32* gflat  = (u32*)(ws + OFF_GFLAT);
  u32* gsbits = (u32*)(ws + OFF_GSB);
  float* qx1  = (float*)(ws + OFF_QX1);
  float* qy1  = (float*)(ws + OFF_QY1);
  float* qx2  = (float*)(ws + OFF_QX2);
  float* qy2  = (float*)(ws + OFF_QY2);
  float* area = (float*)(ws + OFF_AREA);
  float* score= (float*)(ws + OFF_SCORE);
  u32* label  = (u32*)(ws + OFF_LABEL);
  u32* valid  = (u32*)(ws + OFF_VALID);
  float* obox = (float*)(ws + OFF_OBOX);
  float* out  = (float*)d_out;

  kA<<<48, 256, 0, stream>>>(hist, cnt, gsbits, gflat);
  kB_s<<<492, 256, 0, stream>>>(cls0, cls1, cls2, obj0, obj1, obj2, hist);
  k2<<<3, 64, 0, stream>>>(hist, cnt);
  k3<<<7875, 256, 0, stream>>>(cls0, cls1, cls2, obj0, obj1, obj2, cnt, cand);
  r1<<<384, 64, 0, stream>>>(cand, cnt, gsbits, gflat);
  rk6<<<47, 64, 0, stream>>>(reg0, reg1, reg2, gsbits, gflat,
                             qx1, qy1, qx2, qy2, area, score, label, valid, obox, out);
  k7<<<80, 64, 0, stream>>>(qx1, qy1, qx2, qy2, area, score, label, valid, obox, out);
}